// Round 8
// baseline (127.462 us; speedup 1.0000x reference)
//
#include <hip/hip_runtime.h>

#define DIM 128
#define NHEAD 64
#define NROT 8128
#define NSEG 10
#define MHEAD 89088            // sum of n_s^2 floats per head
#define NUNIT 18               // chain (seg,colblock) units per head
#define TBL   16256            // cs floats per head (2*NROT)

typedef float f4 __attribute__((ext_vector_type(4)));

__device__ const int SEG_A[NSEG]   = {0,8,16,24,32,40,48,56,64,80};
__device__ const int SEG_NG[NSEG]  = {1,1,1,1,1,1,1,1,2,6};
__device__ const int SEG_N[NSEG]   = {128,120,112,104,96,88,80,72,64,48};
__device__ const int SEG_OFF[NSEG] = {0,16384,30784,43328,54144,63360,71104,77504,82688,86784};
__device__ const int GSTART[NSEG]  = {0,1,2,3,4,5,6,7,8,10};
__device__ const signed char U_SEG[NUNIT] = {0,0,1,1,2,2,3,3,4,4,5,5,6,6,7,7,8,9};
__device__ const signed char U_CB[NUNIT]  = {0,1,0,1,0,1,0,1,0,1,0,1,0,1,0,1,0,0};
// cs-table float offset of group g: 2040g - 64g^2 ; pair offset: 1020g - 32g^2
__device__ const int GOFF[17] = {0,1976,3824,5544,7136,8600,9936,11144,12224,
                                 13176,14000,14696,15264,15704,16016,16200,16256};
__device__ const int GPO[17]  = {0,988,1912,2772,3568,4300,4968,5572,6112,
                                 6588,7000,7348,7632,7852,8008,8100,8128};

// |theta| <= ~0.06: degree-5/4 Taylor, error ~1e-11
__device__ __forceinline__ void sincos_poly(float x, float& sn, float& cn) {
    float x2 = x * x;
    sn = x * fmaf(x2, fmaf(x2, 8.33333333e-3f, -1.66666667e-1f), 1.0f);
    cn = fmaf(x2, fmaf(x2, 4.16666667e-2f, -0.5f), 1.0f);
}

struct Row { f4 q0, q1, q2, q3; };

#define ROTP(c, s, T, v) { float pt = p[T]; p[T] = fmaf((c), pt, (s) * (v)); \
                           (v) = fmaf((c), (v), -((s) * pt)); }

__device__ __forceinline__ void rot8(const Row& r, float p[8], float& v) {
    ROTP(r.q0.x, r.q0.y, 0, v) ROTP(r.q0.z, r.q0.w, 1, v)
    ROTP(r.q1.x, r.q1.y, 2, v) ROTP(r.q1.z, r.q1.w, 3, v)
    ROTP(r.q2.x, r.q2.y, 4, v) ROTP(r.q2.z, r.q2.w, 5, v)
    ROTP(r.q3.x, r.q3.y, 6, v) ROTP(r.q3.z, r.q3.w, 7, v)
}

__device__ __forceinline__ void ldrow_u(Row& R, const float* p) {
    const f4* c4 = (const f4*)p;
    R.q0 = c4[0]; R.q1 = c4[1]; R.q2 = c4[2]; R.q3 = c4[3];
}

// XOR-swizzled Q: row access 2-way free; transposed (col fixed) access 2-way free.
#define QA(r, c) Q[(r)][ (c) ^ ((r) & 31) ]

// ---- k0: cs table in exact consumption order: per head, groups g=0..15:
// [56 intra floats (28 lex pairs)] [ntr rows x 16 floats (t=0..7 c,s pairs)] ----
__global__ __launch_bounds__(256)
void cs_fill(const float* __restrict__ thetas, float* __restrict__ tab)
{
    const int tid  = blockIdx.x * 256 + threadIdx.x;   // exactly 64*8128 threads
    const int head = tid / NROT;
    const int slot = tid - head * NROT;

    int g = 0;
    #pragma unroll 1
    while (slot >= GPO[g + 1]) ++g;
    const int pos = slot - GPO[g];
    const int a0  = 8 * g;

    int a, off;
    if (pos < 28) {                        // intra, lex (t1,t2)
        int t1 = 0, rem = pos;
        while (rem >= 7 - t1) { rem -= 7 - t1; ++t1; }
        a   = a0 + t1;
        off = (t1 + 1 + rem) - t1 - 1;     // t2 - t1 - 1
    } else {                               // trailing: e = 8*jrel + t
        int e = pos - 28;
        a   = a0 + (e & 7);
        off = (a0 + 8 + (e >> 3)) - a - 1;
    }
    const int r = ((a * (2 * DIM - 1 - a)) >> 1) + off;
    float sn, cn; sincos_poly(thetas[head * NROT + r], sn, cn);
    float2 v; v.x = cn; v.y = sn;
    *(float2*)&tab[(size_t)head * TBL + GOFF[g] + 2 * pos] = v;
}

// ---- Phase 1 (fast path): barrier-free per-segment chain, cs streamed from
// global via uniform (scalarizable) loads. ----
__global__ __launch_bounds__(64, 1)
void chain_tab(const float* __restrict__ tab, float* __restrict__ dst)
{
    __shared__ float Q[DIM][64];           // 32 KB -> 5 blocks/CU

    const int lane = threadIdx.x;
    const int head = blockIdx.x & 63;
    const int unit = blockIdx.x >> 6;
    const int s  = U_SEG[unit], cb = U_CB[unit];
    const int P  = SEG_A[s], n = SEG_N[s];
    const int g0 = GSTART[s], ng = SEG_NG[s];
    const int col_glob = P + cb * 64 + lane;
    const float* __restrict__ csb = tab + (size_t)head * TBL;

    for (int r = P; r < DIM; ++r)
        QA(r, lane) = (r == col_glob) ? 1.0f : 0.0f;
    // no barrier: every lane touches only its own column slots

    #pragma unroll 1
    for (int gi = 0; gi < ng; ++gi) {
        const int g  = g0 + gi;
        const int a0 = 8 * g;
        const float* __restrict__ cs = csb + GOFF[g];

        float p[8];
        #pragma unroll
        for (int t = 0; t < 8; ++t) p[t] = QA(a0 + t, lane);

        // intra-group 28 rotations (uniform cs reads)
        {
            int idx = 0;
            #pragma unroll
            for (int t1 = 0; t1 < 8; ++t1) {
                #pragma unroll
                for (int t2 = t1 + 1; t2 < 8; ++t2) {
                    float c = cs[2 * idx], sn = cs[2 * idx + 1];
                    float pa = p[t1];
                    p[t1] = fmaf(c, pa,    sn * p[t2]);
                    p[t2] = fmaf(c, p[t2], -(sn * pa));
                    ++idx;
                }
            }
        }

        const int ntr = 120 - a0;          // multiple of 8 (0 for g=15)
        if (ntr > 0) {
            const float* __restrict__ ct = cs + 56;
            const int base = a0 + 8;
            float vA = QA(base, lane), vB = QA(base + 1, lane);
            #pragma unroll 1
            for (int r = 0; r < ntr; r += 2) {
                const int rp = (r + 2 < ntr) ? r + 2 : 0;   // clamped prefetch
                float vC = QA(base + rp, lane);
                float vD = QA(base + rp + 1, lane);
                Row R0, R1;
                ldrow_u(R0, ct + 16 * r);
                ldrow_u(R1, ct + 16 * r + 16);
                rot8(R0, p, vA); QA(base + r, lane)     = vA;
                rot8(R1, p, vB); QA(base + r + 1, lane) = vB;
                vA = vC; vB = vD;
            }
        }

        #pragma unroll
        for (int t = 0; t < 8; ++t) QA(a0 + t, lane) = p[t];
    }

    __syncthreads();                       // M^T store reads other columns

    // store M^T: MT[c][r] = Q[P+r][c], coalesced over r
    const int ncol = (n - cb * 64) < 64 ? (n - cb * 64) : 64;
    float* o = dst + (size_t)head * MHEAD + SEG_OFF[s];
    #pragma unroll 1
    for (int cc = 0; cc < ncol; ++cc) {
        const int cg = cb * 64 + cc;
        if (lane < n)      o[cg * n + lane]      = QA(P + lane, cc);
        if (lane + 64 < n) o[cg * n + lane + 64] = QA(P + lane + 64, cc);
    }
}

// ---- Phase 1 (fallback): R7 inline-theta chain (mono or segmented) ----
__global__ __launch_bounds__(64, 1)
void chain_inline(const float* __restrict__ th_all, float* __restrict__ dst, int mono)
{
    __shared__ float Q[DIM][64];
    __shared__ __align__(16) float csx[56 + 8 * 120 * 2];

    const int lane = threadIdx.x;
    const int head = blockIdx.x & 63;
    const int unit = blockIdx.x >> 6;

    int s, cb, ng, n;
    if (mono) { s = 0; cb = unit; ng = 16; n = 128; }
    else      { s = U_SEG[unit]; cb = U_CB[unit]; ng = SEG_NG[s]; n = SEG_N[s]; }
    const int P = mono ? 0 : SEG_A[s];
    const int col_glob = P + cb * 64 + lane;
    const float* __restrict__ th = th_all + head * NROT;

    for (int r = P; r < DIM; ++r)
        QA(r, lane) = (r == col_glob) ? 1.0f : 0.0f;

    #pragma unroll 1
    for (int g = 0; g < ng; ++g) {
        const int a0  = P + 8 * g;
        const int ntr = 120 - a0;
        const int ne  = 8 * ntr;

        __syncthreads();
        float thx[15];
        #pragma unroll
        for (int it = 0; it < 15; ++it) {
            if (it * 64 < ne) {
                int e = lane + it * 64;
                int t = e & 7, jrel = e >> 3;
                int i = a0 + t;
                thx[it] = th[((i * (255 - i)) >> 1) + jrel + 7 - t];
            }
        }
        float thi = 0.0f;
        if (lane < 28) {
            int t1 = 0, rem = lane;
            while (rem >= 7 - t1) { rem -= 7 - t1; ++t1; }
            int t2 = t1 + 1 + rem;
            int i  = a0 + t1;
            thi = th[((i * (255 - i)) >> 1) + (t2 - t1 - 1)];
        }
        #pragma unroll
        for (int it = 0; it < 15; ++it) {
            if (it * 64 < ne) {
                int e = lane + it * 64;
                float sn, cn; sincos_poly(thx[it], sn, cn);
                csx[56 + 2 * e] = cn; csx[56 + 2 * e + 1] = sn;
            }
        }
        if (lane < 28) {
            float sn, cn; sincos_poly(thi, sn, cn);
            csx[2 * lane] = cn; csx[2 * lane + 1] = sn;
        }
        __syncthreads();

        float p[8];
        #pragma unroll
        for (int t = 0; t < 8; ++t) p[t] = QA(a0 + t, lane);
        {
            int idx = 0;
            #pragma unroll
            for (int t1 = 0; t1 < 8; ++t1) {
                #pragma unroll
                for (int t2 = t1 + 1; t2 < 8; ++t2) {
                    float c = csx[2 * idx], sn = csx[2 * idx + 1];
                    float pa = p[t1];
                    p[t1] = fmaf(c, pa,    sn * p[t2]);
                    p[t2] = fmaf(c, p[t2], -(sn * pa));
                    ++idx;
                }
            }
        }
        if (ntr > 0) {
            const float* cs = csx + 56;
            const int base = a0 + 8;
            Row A0, A1, B0, B1;
            float vA0, vA1, vB0, vB1;
            auto ldrow = [&](Row& R, float& v, int r) {
                ldrow_u(R, cs + 16 * r);
                v = QA(base + r, lane);
            };
            ldrow(A0, vA0, 0); ldrow(A1, vA1, 1);
            #pragma unroll 1
            for (int r = 0; r < ntr; r += 4) {
                ldrow(B0, vB0, r + 2); ldrow(B1, vB1, r + 3);
                rot8(A0, p, vA0); rot8(A1, p, vA1);
                QA(base + r, lane)     = vA0;
                QA(base + r + 1, lane) = vA1;
                if (r + 4 < ntr) { ldrow(A0, vA0, r + 4); ldrow(A1, vA1, r + 5); }
                rot8(B0, p, vB0); rot8(B1, p, vB1);
                QA(base + r + 2, lane) = vB0;
                QA(base + r + 3, lane) = vB1;
            }
        }
        #pragma unroll
        for (int t = 0; t < 8; ++t) QA(a0 + t, lane) = p[t];
    }

    __syncthreads();

    if (mono) {
        float* o = dst + head * (DIM * DIM) + col_glob;
        #pragma unroll 1
        for (int r = 0; r < DIM; ++r) o[r * DIM] = QA(r, lane);
    } else {
        const int ncol = (n - cb * 64) < 64 ? (n - cb * 64) : 64;
        float* o = dst + (size_t)head * MHEAD + SEG_OFF[s];
        #pragma unroll 1
        for (int cc = 0; cc < ncol; ++cc) {
            const int cg = cb * 64 + cc;
            if (lane < n)      o[cg * n + lane]      = QA(P + lane, cc);
            if (lane + 64 < n) o[cg * n + lane + 64] = QA(P + lane + 64, cc);
        }
    }
}

// ---- Phase 2: compose, 16-col slices (512 blocks -> 2 blocks/CU) ----
__device__ __forceinline__ void fma4(f4& acc, float m, const f4& a) {
    acc.x = fmaf(m, a.x, acc.x); acc.y = fmaf(m, a.y, acc.y);
    acc.z = fmaf(m, a.z, acc.z); acc.w = fmaf(m, a.w, acc.w);
}

__global__ __launch_bounds__(256, 1)
void compose(const float* __restrict__ M, float* __restrict__ out)
{
    __shared__ float A_sh[DIM][20];          // 10 KB

    const int tid  = threadIdx.x;
    const int head = blockIdx.x & 63;        // all 8 slices of a head -> same XCD
    const int sl   = blockIdx.x >> 6;
    const int c0   = sl * 16;
    const float* __restrict__ Mh = M + (size_t)head * MHEAD;

    for (int idx = tid; idx < 16 * DIM; idx += 256) {
        int c = idx >> 7, r = idx & 127;
        A_sh[r][c] = Mh[(c0 + c) * DIM + r];     // M0^T, coalesced in r
    }

    const int tx = tid & 3;                  // col group (4 cols)
    const int ty = tid >> 2;                 // row pair 0..63
    const int rb = ty * 2;
    const int cl = tx * 4;

    __syncthreads();

    #pragma unroll 1
    for (int s = 1; s < NSEG; ++s) {
        const int P = SEG_A[s], n = SEG_N[s];
        const bool act = rb < n;
        const int rbs = act ? rb : 0;
        const float* __restrict__ Ms = Mh + SEG_OFF[s];

        f4 acc0 = {0,0,0,0}, acc1 = {0,0,0,0};
        float2 mb[8];
        #pragma unroll
        for (int kk = 0; kk < 8; ++kk)
            mb[kk] = *(const float2*)&Ms[(size_t)kk * n + rbs];

        #pragma unroll 1
        for (int k0 = 0; k0 < n; k0 += 8) {
            float2 mn[8];
            const bool have = (k0 + 8) < n;
            if (have) {
                #pragma unroll
                for (int kk = 0; kk < 8; ++kk)
                    mn[kk] = *(const float2*)&Ms[(size_t)(k0 + 8 + kk) * n + rbs];
            }
            #pragma unroll
            for (int kk = 0; kk < 8; ++kk) {
                const f4 a4 = *(const f4*)&A_sh[P + k0 + kk][cl];
                fma4(acc0, mb[kk].x, a4);
                fma4(acc1, mb[kk].y, a4);
            }
            if (have) {
                #pragma unroll
                for (int kk = 0; kk < 8; ++kk) mb[kk] = mn[kk];
            }
        }

        __syncthreads();
        if (act) {
            *(f4*)&A_sh[P + rb + 0][cl] = acc0;
            *(f4*)&A_sh[P + rb + 1][cl] = acc1;
        }
        __syncthreads();
    }

    float* o = out + (size_t)head * (DIM * DIM) + c0;
    #pragma unroll 1
    for (int idx = tid; idx < DIM * 4; idx += 256) {
        int r = idx >> 2, c4 = (idx & 3) * 4;
        *(f4*)&o[r * DIM + c4] = *(const f4*)&A_sh[r][c4];
    }
}

extern "C" void kernel_launch(void* const* d_in, const int* in_sizes, int n_in,
                              void* d_out, int out_size, void* d_ws, size_t ws_size,
                              hipStream_t stream) {
    const float* thetas = (const float*)d_in[0];
    float* out = (float*)d_out;
    const size_t need_m  = (size_t)NHEAD * MHEAD * sizeof(float);   // 22.8 MB
    const size_t need_cs = (size_t)NHEAD * TBL * sizeof(float);     // 4.2 MB

    if (ws_size >= need_m + need_cs) {
        float* tab = (float*)d_ws;
        float* Mws = (float*)d_ws + (size_t)NHEAD * TBL;
        cs_fill<<<dim3((NHEAD * NROT) / 256), dim3(256), 0, stream>>>(thetas, tab);
        chain_tab<<<dim3(NUNIT * NHEAD), dim3(64), 0, stream>>>(tab, Mws);
        compose<<<dim3(8 * NHEAD), dim3(256), 0, stream>>>(Mws, out);
    } else if (ws_size >= need_m) {
        float* Mws = (float*)d_ws;
        chain_inline<<<dim3(NUNIT * NHEAD), dim3(64), 0, stream>>>(thetas, Mws, 0);
        compose<<<dim3(8 * NHEAD), dim3(256), 0, stream>>>(Mws, out);
    } else {
        chain_inline<<<dim3(2 * NHEAD), dim3(64), 0, stream>>>(thetas, out, 1);
    }
}

// Round 9
// 124.944 us; speedup vs baseline: 1.0202x; 1.0202x over previous
//
#include <hip/hip_runtime.h>

#define DIM 128
#define NHEAD 64
#define NROT 8128
#define NSEG 10
#define MHEAD 89088            // sum of n_s^2 floats per head
#define NUNIT 18               // chain (seg,colblock) units per head
#define CSROWS 64              // trailing rows staged per sub-phase

typedef float f4 __attribute__((ext_vector_type(4)));

__device__ const int SEG_A[NSEG]   = {0,8,16,24,32,40,48,56,64,80};
__device__ const int SEG_NG[NSEG]  = {1,1,1,1,1,1,1,1,2,6};
__device__ const int SEG_N[NSEG]   = {128,120,112,104,96,88,80,72,64,48};
__device__ const int SEG_OFF[NSEG] = {0,16384,30784,43328,54144,63360,71104,77504,82688,86784};
__device__ const signed char U_SEG[NUNIT] = {0,0,1,1,2,2,3,3,4,4,5,5,6,6,7,7,8,9};
__device__ const signed char U_CB[NUNIT]  = {0,1,0,1,0,1,0,1,0,1,0,1,0,1,0,1,0,0};

// |theta| <= ~0.06: degree-5/4 Taylor, error ~1e-11
__device__ __forceinline__ void sincos_poly(float x, float& sn, float& cn) {
    float x2 = x * x;
    sn = x * fmaf(x2, fmaf(x2, 8.33333333e-3f, -1.66666667e-1f), 1.0f);
    cn = fmaf(x2, fmaf(x2, 4.16666667e-2f, -0.5f), 1.0f);
}

struct Row { f4 q0, q1, q2, q3; };

#define ROTP(c, s, T, v) { float pt = p[T]; p[T] = fmaf((c), pt, (s) * (v)); \
                           (v) = fmaf((c), (v), -((s) * pt)); }

__device__ __forceinline__ void rot8(const Row& r, float p[8], float& v) {
    ROTP(r.q0.x, r.q0.y, 0, v) ROTP(r.q0.z, r.q0.w, 1, v)
    ROTP(r.q1.x, r.q1.y, 2, v) ROTP(r.q1.z, r.q1.w, 3, v)
    ROTP(r.q2.x, r.q2.y, 4, v) ROTP(r.q2.z, r.q2.w, 5, v)
    ROTP(r.q3.x, r.q3.y, 6, v) ROTP(r.q3.z, r.q3.w, 7, v)
}

__device__ __forceinline__ void ldrow_u(Row& R, const float* p) {
    const f4* c4 = (const f4*)p;
    R.q0 = c4[0]; R.q1 = c4[1]; R.q2 = c4[2]; R.q3 = c4[3];
}

// XOR-swizzled Q: row access 2-way free; transposed (col fixed) access 2-way free.
#define QA(r, c) Q[(r)][ (c) ^ ((r) & 31) ]

// ---- Phase 1: per-segment chain, inline theta->cs staging (batched loads),
// csx shrunk to a 64-row chunk so LDS ~37.4 KB -> 4 blocks/CU. ----
__global__ __launch_bounds__(64, 1)
void chain(const float* __restrict__ th_all, float* __restrict__ dst, int mono)
{
    __shared__ float Q[DIM][64];                     // 32 KB
    __shared__ __align__(16) float csx[56 + CSROWS * 16];   // 4.3 KB

    const int lane = threadIdx.x;
    const int head = blockIdx.x & 63;                // XCD = head%8 for all units
    const int unit = blockIdx.x >> 6;

    int s, cb, ng, n;
    if (mono) { s = 0; cb = unit; ng = 16; n = 128; }
    else      { s = U_SEG[unit]; cb = U_CB[unit]; ng = SEG_NG[s]; n = SEG_N[s]; }
    const int P = mono ? 0 : SEG_A[s];
    const int col_glob = P + cb * 64 + lane;
    const float* __restrict__ th = th_all + head * NROT;

    for (int r = P; r < DIM; ++r)
        QA(r, lane) = (r == col_glob) ? 1.0f : 0.0f;

    #pragma unroll 1
    for (int g = 0; g < ng; ++g) {
        const int a0  = P + 8 * g;
        const int ntr = 120 - a0;                    // multiple of 8, may be 0
        float p[8];

        const int nsub = (ntr > CSROWS) ? 2 : 1;
        #pragma unroll 1
        for (int sub = 0; sub < nsub; ++sub) {
            const int r0 = sub * CSROWS;
            const int nr = (ntr - r0) < CSROWS ? (ntr - r0) : CSROWS;  // mult of 8, >=0
            const int ne = 8 * nr;

            __syncthreads();                         // csx reuse guard
            // batched theta loads (independent -> one latency exposure)
            float thx[8];
            #pragma unroll
            for (int it = 0; it < 8; ++it) {
                if (it * 64 < ne) {
                    int e = lane + it * 64;
                    int t = e & 7, jr = r0 + (e >> 3);
                    int i = a0 + t;
                    thx[it] = th[((i * (255 - i)) >> 1) + jr + 7 - t];
                }
            }
            float thi = 0.0f;
            if (sub == 0 && lane < 28) {
                int t1 = 0, rem = lane;
                while (rem >= 7 - t1) { rem -= 7 - t1; ++t1; }
                int t2 = t1 + 1 + rem;
                int i  = a0 + t1;
                thi = th[((i * (255 - i)) >> 1) + (t2 - t1 - 1)];
            }
            #pragma unroll
            for (int it = 0; it < 8; ++it) {
                if (it * 64 < ne) {
                    int e = lane + it * 64;
                    float sn, cn; sincos_poly(thx[it], sn, cn);
                    csx[56 + 2 * e] = cn; csx[56 + 2 * e + 1] = sn;
                }
            }
            if (sub == 0 && lane < 28) {
                float sn, cn; sincos_poly(thi, sn, cn);
                csx[2 * lane] = cn; csx[2 * lane + 1] = sn;
            }
            __syncthreads();

            if (sub == 0) {
                #pragma unroll
                for (int t = 0; t < 8; ++t) p[t] = QA(a0 + t, lane);
                // intra-group 28 rotations
                int idx = 0;
                #pragma unroll
                for (int t1 = 0; t1 < 8; ++t1) {
                    #pragma unroll
                    for (int t2 = t1 + 1; t2 < 8; ++t2) {
                        float c = csx[2 * idx], sn = csx[2 * idx + 1];
                        float pa = p[t1];
                        p[t1] = fmaf(c, pa,    sn * p[t2]);
                        p[t2] = fmaf(c, p[t2], -(sn * pa));
                        ++idx;
                    }
                }
            }

            if (nr > 0) {
                const float* cs = csx + 56;          // local row indexing
                const int base = a0 + 8 + r0;
                Row A0, A1, B0, B1;
                float vA0, vA1, vB0, vB1;
                auto ldpair = [&](Row& R, float& v, int r) {
                    ldrow_u(R, cs + 16 * r);
                    v = QA(base + r, lane);
                };
                ldpair(A0, vA0, 0); ldpair(A1, vA1, 1);
                #pragma unroll 1
                for (int r = 0; r < nr; r += 4) {
                    ldpair(B0, vB0, r + 2); ldpair(B1, vB1, r + 3);
                    rot8(A0, p, vA0); rot8(A1, p, vA1);
                    QA(base + r, lane)     = vA0;
                    QA(base + r + 1, lane) = vA1;
                    if (r + 4 < nr) { ldpair(A0, vA0, r + 4); ldpair(A1, vA1, r + 5); }
                    rot8(B0, p, vB0); rot8(B1, p, vB1);
                    QA(base + r + 2, lane) = vB0;
                    QA(base + r + 3, lane) = vB1;
                }
            }
        }

        #pragma unroll
        for (int t = 0; t < 8; ++t) QA(a0 + t, lane) = p[t];
    }

    __syncthreads();                                 // M^T store reads other columns

    if (mono) {
        float* o = dst + head * (DIM * DIM) + col_glob;
        #pragma unroll 1
        for (int r = 0; r < DIM; ++r) o[r * DIM] = QA(r, lane);
    } else {
        // store M^T: MT[c][r] = Q[P+r][c], coalesced over r, swizzle-conflict-free
        const int ncol = (n - cb * 64) < 64 ? (n - cb * 64) : 64;
        float* o = dst + (size_t)head * MHEAD + SEG_OFF[s];
        #pragma unroll 1
        for (int cc = 0; cc < ncol; ++cc) {
            const int cg = cb * 64 + cc;
            if (lane < n)      o[cg * n + lane]      = QA(P + lane, cc);
            if (lane + 64 < n) o[cg * n + lane + 64] = QA(P + lane + 64, cc);
        }
    }
}

// ---- Phase 2: compose, split-K x2, 512 threads, 2-deep register prefetch ----
__device__ __forceinline__ void fma4(f4& acc, float m, const f4& a) {
    acc.x = fmaf(m, a.x, acc.x); acc.y = fmaf(m, a.y, acc.y);
    acc.z = fmaf(m, a.z, acc.z); acc.w = fmaf(m, a.w, acc.w);
}

__global__ __launch_bounds__(512, 4)
void compose(const float* __restrict__ M, float* __restrict__ out)
{
    __shared__ float A_sh[DIM][20];          // 10 KB
    __shared__ f4 red0[256], red1[256];      // 8 KB k-split reduce

    const int tid  = threadIdx.x;
    const int t    = tid & 255;
    const int kh   = tid >> 8;               // k-half 0/1
    const int head = blockIdx.x & 63;        // all 8 slices of a head -> same XCD
    const int sl   = blockIdx.x >> 6;
    const int c0   = sl * 16;
    const float* __restrict__ Mh = M + (size_t)head * MHEAD;

    for (int idx = tid; idx < 16 * DIM; idx += 512) {
        int c = idx >> 7, r = idx & 127;
        A_sh[r][c] = Mh[(c0 + c) * DIM + r];     // M0^T, coalesced in r
    }

    const int tx = t & 3;                    // col group (4 cols)
    const int ty = t >> 2;                   // row pair 0..63
    const int rb = ty * 2;
    const int cl = tx * 4;

    __syncthreads();

    #pragma unroll 1
    for (int s = 1; s < NSEG; ++s) {
        const int P = SEG_A[s], n = SEG_N[s];
        const int n1   = 8 * ((n + 15) / 16);            // k split point (mult of 8)
        const int kbeg = kh ? n1 : 0;
        const int kend = kh ? n  : n1;
        const bool act = rb < n;
        const int rbs  = act ? rb : 0;                   // clamp: no OOB loads
        const float* __restrict__ Ms = Mh + SEG_OFF[s];

        f4 acc0 = {0,0,0,0}, acc1 = {0,0,0,0};
        float2 bA[8], bB[8];
        #pragma unroll
        for (int kk = 0; kk < 8; ++kk) {
            int ka = kbeg + kk,     kb = kbeg + 8 + kk;
            bA[kk] = *(const float2*)&Ms[(size_t)(ka < n ? ka : 0) * n + rbs];
            bB[kk] = *(const float2*)&Ms[(size_t)(kb < n ? kb : 0) * n + rbs];
        }

        #pragma unroll 1
        for (int k0 = kbeg; k0 < kend; k0 += 16) {
            float2 nA[8], nB[8];
            const bool haveA = (k0 + 16) < kend;
            const bool haveB = (k0 + 24) < kend;
            if (haveA) {
                #pragma unroll
                for (int kk = 0; kk < 8; ++kk)
                    nA[kk] = *(const float2*)&Ms[(size_t)(k0 + 16 + kk) * n + rbs];
            }
            #pragma unroll
            for (int kk = 0; kk < 8; ++kk) {             // chunk A: k0..k0+8
                const f4 a4 = *(const f4*)&A_sh[P + k0 + kk][cl];
                fma4(acc0, bA[kk].x, a4);
                fma4(acc1, bA[kk].y, a4);
            }
            if (haveB) {
                #pragma unroll
                for (int kk = 0; kk < 8; ++kk)
                    nB[kk] = *(const float2*)&Ms[(size_t)(k0 + 24 + kk) * n + rbs];
            }
            if (k0 + 8 < kend) {
                #pragma unroll
                for (int kk = 0; kk < 8; ++kk) {         // chunk B: k0+8..k0+16
                    const f4 a4 = *(const f4*)&A_sh[P + k0 + 8 + kk][cl];
                    fma4(acc0, bB[kk].x, a4);
                    fma4(acc1, bB[kk].y, a4);
                }
            }
            #pragma unroll
            for (int kk = 0; kk < 8; ++kk) { bA[kk] = nA[kk]; bB[kk] = nB[kk]; }
        }

        if (kh) { red0[t] = acc0; red1[t] = acc1; }
        __syncthreads();                      // also covers: all reads of old A done
        if (!kh && act) {
            acc0 += red0[t]; acc1 += red1[t];
            *(f4*)&A_sh[P + rb + 0][cl] = acc0;
            *(f4*)&A_sh[P + rb + 1][cl] = acc1;
        }
        __syncthreads();                      // new A visible
    }

    float* o = out + (size_t)head * (DIM * DIM) + c0;
    #pragma unroll 1
    for (int idx = tid; idx < DIM * 4; idx += 512) {
        int r = idx >> 2, c4 = (idx & 3) * 4;
        *(f4*)&o[r * DIM + c4] = *(const f4*)&A_sh[r][c4];
    }
}

extern "C" void kernel_launch(void* const* d_in, const int* in_sizes, int n_in,
                              void* d_out, int out_size, void* d_ws, size_t ws_size,
                              hipStream_t stream) {
    const float* thetas = (const float*)d_in[0];
    float* out = (float*)d_out;
    const size_t need_m = (size_t)NHEAD * MHEAD * sizeof(float);   // 22.8 MB

    if (ws_size >= need_m) {
        float* Mws = (float*)d_ws;
        chain<<<dim3(NUNIT * NHEAD), dim3(64), 0, stream>>>(thetas, Mws, 0);
        compose<<<dim3(8 * NHEAD), dim3(512), 0, stream>>>(Mws, out);
    } else {
        chain<<<dim3(2 * NHEAD), dim3(64), 0, stream>>>(thetas, out, 1);
    }
}

// Round 10
// 71.899 us; speedup vs baseline: 1.7728x; 1.7378x over previous
//
#include <hip/hip_runtime.h>

#define DIM 128
#define NHEAD 64
#define NROT 8128
#define NSEG 10
#define MHEAD 89088            // sum of n_s^2 elements per head
#define NUNIT 18               // chain (seg,colblock) units per head
#define CSROWS 64              // trailing rows staged per sub-phase
#define KA 216                 // compose LDS k-dim (128 data + pad, 432B stride)

typedef float f4 __attribute__((ext_vector_type(4)));
typedef short bf8 __attribute__((ext_vector_type(8)));
typedef unsigned short u16;

__device__ const int SEG_A[NSEG]   = {0,8,16,24,32,40,48,56,64,80};
__device__ const int SEG_NG[NSEG]  = {1,1,1,1,1,1,1,1,2,6};
__device__ const int SEG_N[NSEG]   = {128,120,112,104,96,88,80,72,64,48};
__device__ const int SEG_OFF[NSEG] = {0,16384,30784,43328,54144,63360,71104,77504,82688,86784};
__device__ const signed char U_SEG[NUNIT] = {0,0,1,1,2,2,3,3,4,4,5,5,6,6,7,7,8,9};
__device__ const signed char U_CB[NUNIT]  = {0,1,0,1,0,1,0,1,0,1,0,1,0,1,0,1,0,0};

// |theta| <= ~0.06: degree-5/4 Taylor, error ~1e-11
__device__ __forceinline__ void sincos_poly(float x, float& sn, float& cn) {
    float x2 = x * x;
    sn = x * fmaf(x2, fmaf(x2, 8.33333333e-3f, -1.66666667e-1f), 1.0f);
    cn = fmaf(x2, fmaf(x2, 4.16666667e-2f, -0.5f), 1.0f);
}

__device__ __forceinline__ u16 f2bf(float v) {          // RNE f32 -> bf16 bits
    unsigned b = __float_as_uint(v);
    b += 0x7FFF + ((b >> 16) & 1);
    return (u16)(b >> 16);
}
__device__ __forceinline__ float bf2f(u16 h) {
    return __uint_as_float(((unsigned)h) << 16);
}

struct Row { f4 q0, q1, q2, q3; };

#define ROTP(c, s, T, v) { float pt = p[T]; p[T] = fmaf((c), pt, (s) * (v)); \
                           (v) = fmaf((c), (v), -((s) * pt)); }

__device__ __forceinline__ void rot8(const Row& r, float p[8], float& v) {
    ROTP(r.q0.x, r.q0.y, 0, v) ROTP(r.q0.z, r.q0.w, 1, v)
    ROTP(r.q1.x, r.q1.y, 2, v) ROTP(r.q1.z, r.q1.w, 3, v)
    ROTP(r.q2.x, r.q2.y, 4, v) ROTP(r.q2.z, r.q2.w, 5, v)
    ROTP(r.q3.x, r.q3.y, 6, v) ROTP(r.q3.z, r.q3.w, 7, v)
}

__device__ __forceinline__ void ldrow_u(Row& R, const float* p) {
    const f4* c4 = (const f4*)p;
    R.q0 = c4[0]; R.q1 = c4[1]; R.q2 = c4[2]; R.q3 = c4[3];
}

// XOR-swizzled Q: row access 2-way free; transposed access 2-way free.
#define QA(r, c) Q[(r)][ (c) ^ ((r) & 31) ]

// ---- Phase 1: per-segment chain (R9 compute, bf16-pair M output) ----
__global__ __launch_bounds__(64, 1)
void chain(const float* __restrict__ th_all, float* __restrict__ dst_f32,
           u16* __restrict__ MhW, u16* __restrict__ MlW, int mono)
{
    __shared__ float Q[DIM][64];                     // 32 KB
    __shared__ __align__(16) float csx[56 + CSROWS * 16];   // 4.3 KB

    const int lane = threadIdx.x;
    const int head = blockIdx.x & 63;
    const int unit = blockIdx.x >> 6;

    int s, cb, ng, n;
    if (mono) { s = 0; cb = unit; ng = 16; n = 128; }
    else      { s = U_SEG[unit]; cb = U_CB[unit]; ng = SEG_NG[s]; n = SEG_N[s]; }
    const int P = mono ? 0 : SEG_A[s];
    const int col_local = cb * 64 + lane;
    const int col_glob  = P + col_local;
    const float* __restrict__ th = th_all + head * NROT;

    for (int r = P; r < DIM; ++r)
        QA(r, lane) = (r == col_glob) ? 1.0f : 0.0f;

    #pragma unroll 1
    for (int g = 0; g < ng; ++g) {
        const int a0  = P + 8 * g;
        const int ntr = 120 - a0;                    // multiple of 8, may be 0
        float p[8];

        const int nsub = (ntr > CSROWS) ? 2 : 1;
        #pragma unroll 1
        for (int sub = 0; sub < nsub; ++sub) {
            const int r0 = sub * CSROWS;
            const int nr = (ntr - r0) < CSROWS ? (ntr - r0) : CSROWS;
            const int ne = 8 * nr;

            __syncthreads();
            float thx[8];
            #pragma unroll
            for (int it = 0; it < 8; ++it) {
                if (it * 64 < ne) {
                    int e = lane + it * 64;
                    int t = e & 7, jr = r0 + (e >> 3);
                    int i = a0 + t;
                    thx[it] = th[((i * (255 - i)) >> 1) + jr + 7 - t];
                }
            }
            float thi = 0.0f;
            if (sub == 0 && lane < 28) {
                int t1 = 0, rem = lane;
                while (rem >= 7 - t1) { rem -= 7 - t1; ++t1; }
                int t2 = t1 + 1 + rem;
                int i  = a0 + t1;
                thi = th[((i * (255 - i)) >> 1) + (t2 - t1 - 1)];
            }
            #pragma unroll
            for (int it = 0; it < 8; ++it) {
                if (it * 64 < ne) {
                    int e = lane + it * 64;
                    float sn, cn; sincos_poly(thx[it], sn, cn);
                    csx[56 + 2 * e] = cn; csx[56 + 2 * e + 1] = sn;
                }
            }
            if (sub == 0 && lane < 28) {
                float sn, cn; sincos_poly(thi, sn, cn);
                csx[2 * lane] = cn; csx[2 * lane + 1] = sn;
            }
            __syncthreads();

            if (sub == 0) {
                #pragma unroll
                for (int t = 0; t < 8; ++t) p[t] = QA(a0 + t, lane);
                int idx = 0;
                #pragma unroll
                for (int t1 = 0; t1 < 8; ++t1) {
                    #pragma unroll
                    for (int t2 = t1 + 1; t2 < 8; ++t2) {
                        float c = csx[2 * idx], sn = csx[2 * idx + 1];
                        float pa = p[t1];
                        p[t1] = fmaf(c, pa,    sn * p[t2]);
                        p[t2] = fmaf(c, p[t2], -(sn * pa));
                        ++idx;
                    }
                }
            }

            if (nr > 0) {
                const float* cs = csx + 56;
                const int base = a0 + 8 + r0;
                Row A0, A1, B0, B1;
                float vA0, vA1, vB0, vB1;
                auto ldpair = [&](Row& R, float& v, int r) {
                    ldrow_u(R, cs + 16 * r);
                    v = QA(base + r, lane);
                };
                ldpair(A0, vA0, 0); ldpair(A1, vA1, 1);
                #pragma unroll 1
                for (int r = 0; r < nr; r += 4) {
                    ldpair(B0, vB0, r + 2); ldpair(B1, vB1, r + 3);
                    rot8(A0, p, vA0); rot8(A1, p, vA1);
                    QA(base + r, lane)     = vA0;
                    QA(base + r + 1, lane) = vA1;
                    if (r + 4 < nr) { ldpair(A0, vA0, r + 4); ldpair(A1, vA1, r + 5); }
                    rot8(B0, p, vB0); rot8(B1, p, vB1);
                    QA(base + r + 2, lane) = vB0;
                    QA(base + r + 3, lane) = vB1;
                }
            }
        }

        #pragma unroll
        for (int t = 0; t < 8; ++t) QA(a0 + t, lane) = p[t];
    }

    __syncthreads();

    if (mono) {
        float* o = dst_f32 + head * (DIM * DIM) + col_glob;
        #pragma unroll 1
        for (int r = 0; r < DIM; ++r) o[r * DIM] = QA(r, lane);
    } else if (col_local < n) {
        // M row-major bf16 pair: Mh[r][c] + Ml[r][c]; coalesced u16 stores over lane
        u16* oh = MhW + (size_t)head * MHEAD + SEG_OFF[s];
        u16* ol = MlW + (size_t)head * MHEAD + SEG_OFF[s];
        #pragma unroll 2
        for (int r = 0; r < n; ++r) {
            float v = QA(P + r, lane);
            u16 h = f2bf(v);
            u16 l = f2bf(v - bf2f(h));
            oh[r * n + col_local] = h;
            ol[r * n + col_local] = l;
        }
    }
}

// ---- Phase 2: MFMA compose with bf16 3-term split (Markidis) ----
// Block = (head, 32-col quarter), 4 waves. A in LDS col-major bf16 pair
// A*T[c][k], k-pad rows [128,KA) zeroed => padded k contributes exact 0.
// Per seg: 8 row-tiles x 2 col-tiles, wave w owns rt {w, w+4}; 4 k-steps.
__global__ __launch_bounds__(256, 1)
void compose_mfma(const u16* __restrict__ MhA, const u16* __restrict__ MlA,
                  float* __restrict__ out)
{
    __shared__ u16 AhT[32][KA];          // 13.5 KB
    __shared__ u16 AlT[32][KA];          // 13.5 KB

    const int tid  = threadIdx.x;
    const int lane = tid & 63;
    const int w    = tid >> 6;
    const int head = blockIdx.x & 63;    // all 4 quarters of a head -> same XCD
    const int cq   = blockIdx.x >> 6;
    const int c0   = cq * 32;
    const u16* __restrict__ Mh = MhA + (size_t)head * MHEAD;
    const u16* __restrict__ Ml = MlA + (size_t)head * MHEAD;

    // zero k-pad, then A := M0 slice
    {
        int c = tid & 31;
        for (int k = DIM + (tid >> 5); k < KA; k += 8) { AhT[c][k] = 0; AlT[c][k] = 0; }
        for (int r = tid >> 5; r < DIM; r += 8) {
            AhT[c][r] = Mh[r * DIM + c0 + c];
            AlT[c][r] = Ml[r * DIM + c0 + c];
        }
    }
    __syncthreads();

    const int fr  = lane & 15;           // A-frag row / B-frag col within tile
    const int fk  = (lane >> 4) * 8;     // k-slice offset
    const int r4  = (lane >> 4) * 4;     // C/D row offset within tile
    const int ro0 = 16 * w;
    const int ro1 = 16 * (w + 4);

    #pragma unroll 1
    for (int s = 1; s < NSEG; ++s) {
        const int P = SEG_A[s], n = SEG_N[s], off = SEG_OFF[s];
        const u16* __restrict__ Msh = Mh + off;
        const u16* __restrict__ Msl = Ml + off;
        const bool actA = ro0 < n;
        const bool actB = ro1 < n;
        const int rA = ro0 + fr;
        const int rB = ro1 + fr;

        f4 c00 = {0,0,0,0}, c01 = {0,0,0,0}, c10 = {0,0,0,0}, c11 = {0,0,0,0};

        #pragma unroll
        for (int kt = 0; kt < 4; ++kt) {
            const int kk  = kt * 32 + fk;
            const int kkc = (kk <= n - 8) ? kk : (n - 8);   // clamp: stay in-head
            // B frags: A_old, k-contiguous; rows >= 128 are the zero pad
            bf8 bh0 = *(const bf8*)&AhT[fr][P + kk];
            bf8 bl0 = *(const bf8*)&AlT[fr][P + kk];
            bf8 bh1 = *(const bf8*)&AhT[16 + fr][P + kk];
            bf8 bl1 = *(const bf8*)&AlT[16 + fr][P + kk];
            if (actA) {
                const bf8 ah = *(const bf8*)&Msh[rA * n + kkc];
                const bf8 al = *(const bf8*)&Msl[rA * n + kkc];
                c00 = __builtin_amdgcn_mfma_f32_16x16x32_bf16(ah, bh0, c00, 0, 0, 0);
                c00 = __builtin_amdgcn_mfma_f32_16x16x32_bf16(ah, bl0, c00, 0, 0, 0);
                c00 = __builtin_amdgcn_mfma_f32_16x16x32_bf16(al, bh0, c00, 0, 0, 0);
                c01 = __builtin_amdgcn_mfma_f32_16x16x32_bf16(ah, bh1, c01, 0, 0, 0);
                c01 = __builtin_amdgcn_mfma_f32_16x16x32_bf16(ah, bl1, c01, 0, 0, 0);
                c01 = __builtin_amdgcn_mfma_f32_16x16x32_bf16(al, bh1, c01, 0, 0, 0);
            }
            if (actB) {
                const bf8 ah = *(const bf8*)&Msh[rB * n + kkc];
                const bf8 al = *(const bf8*)&Msl[rB * n + kkc];
                c10 = __builtin_amdgcn_mfma_f32_16x16x32_bf16(ah, bh0, c10, 0, 0, 0);
                c10 = __builtin_amdgcn_mfma_f32_16x16x32_bf16(ah, bl0, c10, 0, 0, 0);
                c10 = __builtin_amdgcn_mfma_f32_16x16x32_bf16(al, bh0, c10, 0, 0, 0);
                c11 = __builtin_amdgcn_mfma_f32_16x16x32_bf16(ah, bh1, c11, 0, 0, 0);
                c11 = __builtin_amdgcn_mfma_f32_16x16x32_bf16(ah, bl1, c11, 0, 0, 0);
                c11 = __builtin_amdgcn_mfma_f32_16x16x32_bf16(al, bh1, c11, 0, 0, 0);
            }
        }

        __syncthreads();                 // all reads of old A complete

        // write back new rows (re-split to bf16 pair); rows >= 128 are pad rows
        auto split_store = [&](const f4& cc, int rg, int cL) {
            if (rg < DIM) {
                float v0 = cc[0], v1 = cc[1], v2 = cc[2], v3 = cc[3];
                u16 h0 = f2bf(v0), h1 = f2bf(v1), h2 = f2bf(v2), h3 = f2bf(v3);
                u16 l0 = f2bf(v0 - bf2f(h0)), l1 = f2bf(v1 - bf2f(h1));
                u16 l2 = f2bf(v2 - bf2f(h2)), l3 = f2bf(v3 - bf2f(h3));
                ushort4 hv; hv.x = h0; hv.y = h1; hv.z = h2; hv.w = h3;
                ushort4 lv; lv.x = l0; lv.y = l1; lv.z = l2; lv.w = l3;
                *(ushort4*)&AhT[cL][rg] = hv;
                *(ushort4*)&AlT[cL][rg] = lv;
            }
        };
        split_store(c00, P + ro0 + r4, fr);
        split_store(c01, P + ro0 + r4, 16 + fr);
        split_store(c10, P + ro1 + r4, fr);
        split_store(c11, P + ro1 + r4, 16 + fr);
        __syncthreads();                 // new A visible
    }

    // output: Q = Ah + Al, coalesced f32 stores
    {
        int c = tid & 31;
        float* o = out + (size_t)head * (DIM * DIM) + c0;
        for (int r = tid >> 5; r < DIM; r += 8)
            o[r * DIM + c] = bf2f(AhT[c][r]) + bf2f(AlT[c][r]);
    }
}

extern "C" void kernel_launch(void* const* d_in, const int* in_sizes, int n_in,
                              void* d_out, int out_size, void* d_ws, size_t ws_size,
                              hipStream_t stream) {
    const float* thetas = (const float*)d_in[0];
    float* out = (float*)d_out;
    // Mh + Ml bf16 arrays: 2 * 64 * 89088 * 2B = 22.8 MB (same as prior f32 M)
    const size_t need = (size_t)NHEAD * MHEAD * 2 * sizeof(u16);

    if (ws_size >= need) {
        u16* MhW = (u16*)d_ws;
        u16* MlW = MhW + (size_t)NHEAD * MHEAD;
        chain<<<dim3(NUNIT * NHEAD), dim3(64), 0, stream>>>(thetas, nullptr, MhW, MlW, 0);
        compose_mfma<<<dim3(4 * NHEAD), dim3(256), 0, stream>>>(MhW, MlW, out);
    } else {
        chain<<<dim3(2 * NHEAD), dim3(64), 0, stream>>>(thetas, out, nullptr, nullptr, 1);
    }
}

// Round 11
// 52.156 us; speedup vs baseline: 2.4439x; 1.3785x over previous
//
#include <hip/hip_runtime.h>

#define DIM 128
#define NHEAD 64
#define NROT 8128
#define CSROWS 64
#define KAC 168                // compose LDS k-dim: 8*21 -> 8-distinct-bank stride

#define MHEAD16 95744          // 16-seg: sum n_s^2
#define NUNIT16 24
#define MHEAD10 89088          // 10-seg (R10 mid tier)
#define NUNIT10 18

typedef float f4 __attribute__((ext_vector_type(4)));
typedef short bf8 __attribute__((ext_vector_type(8)));
typedef unsigned short u16;

// ---- 16-seg tables (fast tier): segment s has P=8s, n=128-8s, single group ----
__device__ const int SEG16_OFF[16] = {0,16384,30784,43328,54144,63360,71104,77504,
                                      82688,86784,89920,92224,93824,94848,95424,95680};
__device__ const signed char U16_SEG[NUNIT16] = {0,0,1,1,2,2,3,3,4,4,5,5,6,6,7,7,
                                                 8,9,10,11,12,13,14,15};
__device__ const signed char U16_CB[NUNIT16]  = {0,1,0,1,0,1,0,1,0,1,0,1,0,1,0,1,
                                                 0,0,0,0,0,0,0,0};

// ---- 10-seg tables (mid tier, R10-proven) ----
__device__ const int SEG_A[10]   = {0,8,16,24,32,40,48,56,64,80};
__device__ const int SEG_NG[10]  = {1,1,1,1,1,1,1,1,2,6};
__device__ const int SEG_N[10]   = {128,120,112,104,96,88,80,72,64,48};
__device__ const int SEG_OFF[10] = {0,16384,30784,43328,54144,63360,71104,77504,82688,86784};
__device__ const signed char U_SEG[NUNIT10] = {0,0,1,1,2,2,3,3,4,4,5,5,6,6,7,7,8,9};
__device__ const signed char U_CB[NUNIT10]  = {0,1,0,1,0,1,0,1,0,1,0,1,0,1,0,1,0,0};

// ---- compose tables: cfg 0 = 16-seg, cfg 1 = 10-seg ----
__device__ const int CSEG_CNT[2] = {16, 10};
__device__ const int CSEG_A[2][16] = {
    {0,8,16,24,32,40,48,56,64,72,80,88,96,104,112,120},
    {0,8,16,24,32,40,48,56,64,80,0,0,0,0,0,0}};
__device__ const int CSEG_N[2][16] = {
    {128,120,112,104,96,88,80,72,64,56,48,40,32,24,16,8},
    {128,120,112,104,96,88,80,72,64,48,0,0,0,0,0,0}};
__device__ const int CSEG_OFF[2][16] = {
    {0,16384,30784,43328,54144,63360,71104,77504,82688,86784,89920,92224,93824,94848,95424,95680},
    {0,16384,30784,43328,54144,63360,71104,77504,82688,86784,0,0,0,0,0,0}};

// |theta| <= ~0.06: degree-5/4 Taylor, error ~1e-11
__device__ __forceinline__ void sincos_poly(float x, float& sn, float& cn) {
    float x2 = x * x;
    sn = x * fmaf(x2, fmaf(x2, 8.33333333e-3f, -1.66666667e-1f), 1.0f);
    cn = fmaf(x2, fmaf(x2, 4.16666667e-2f, -0.5f), 1.0f);
}

__device__ __forceinline__ u16 f2bf(float v) {          // RNE f32 -> bf16 bits
    unsigned b = __float_as_uint(v);
    b += 0x7FFF + ((b >> 16) & 1);
    return (u16)(b >> 16);
}
__device__ __forceinline__ float bf2f(u16 h) {
    return __uint_as_float(((unsigned)h) << 16);
}

struct Row { f4 q0, q1, q2, q3; };   // 8 (c,s) pairs for one trailing row

__device__ __forceinline__ void ldrow_u(Row& R, const float* p) {
    const f4* c4 = (const f4*)p;
    R.q0 = c4[0]; R.q1 = c4[1]; R.q2 = c4[2]; R.q3 = c4[3];
}

// v-chain for one trailing row: v_in known constant, p in registers.
__device__ __forceinline__ float rowv(const Row& R, float p[8], float v) {
#define ROT2(c, s, T) { float pv = p[T]; float nv = fmaf((c), v, -((s) * pv)); \
                        p[T] = fmaf((s), v, (c) * pv); v = nv; }
    ROT2(R.q0.x, R.q0.y, 0) ROT2(R.q0.z, R.q0.w, 1)
    ROT2(R.q1.x, R.q1.y, 2) ROT2(R.q1.z, R.q1.w, 3)
    ROT2(R.q2.x, R.q2.y, 4) ROT2(R.q2.z, R.q2.w, 5)
    ROT2(R.q3.x, R.q3.y, 6) ROT2(R.q3.z, R.q3.w, 7)
#undef ROT2
    return v;
}

__device__ __forceinline__ void store_bf(u16* oh, u16* ol, int idx, float v, bool act) {
    u16 h = f2bf(v);
    u16 l = f2bf(v - bf2f(h));
    if (act) { oh[idx] = h; ol[idx] = l; }
}

// legacy rot8 (Q-path mid/mono kernel)
#define ROTP(c, s, T, v) { float pt = p[T]; p[T] = fmaf((c), pt, (s) * (v)); \
                           (v) = fmaf((c), (v), -((s) * pt)); }
__device__ __forceinline__ void rot8(const Row& r, float p[8], float& v) {
    ROTP(r.q0.x, r.q0.y, 0, v) ROTP(r.q0.z, r.q0.w, 1, v)
    ROTP(r.q1.x, r.q1.y, 2, v) ROTP(r.q1.z, r.q1.w, 3, v)
    ROTP(r.q2.x, r.q2.y, 4, v) ROTP(r.q2.z, r.q2.w, 5, v)
    ROTP(r.q3.x, r.q3.y, 6, v) ROTP(r.q3.z, r.q3.w, 7, v)
}

#define QA(r, c) Q[(r)][ (c) ^ ((r) & 31) ]

// ==== Fast-tier chain: Q-LESS single-group segments (16 segs, 24 units/head) ====
__global__ __launch_bounds__(64, 1)
void chain16(const float* __restrict__ th_all,
             u16* __restrict__ MhW, u16* __restrict__ MlW)
{
    __shared__ __align__(16) float csx[56 + CSROWS * 16];   // 4.3 KB ONLY

    const int lane = threadIdx.x;
    const int head = blockIdx.x & 63;
    const int unit = blockIdx.x >> 6;
    const int s  = U16_SEG[unit], cb = U16_CB[unit];
    const int P  = 8 * s, n = DIM - P;
    const int a0 = P;
    const int ntr = n - 8;                       // trailing rows (mult of 8, may be 0)
    const int col_local = cb * 64 + lane;
    const int col_glob  = P + col_local;
    const bool cact = col_local < n;
    const float* __restrict__ th = th_all + head * NROT;
    u16* __restrict__ oh = MhW + (size_t)head * MHEAD16 + SEG16_OFF[s];
    u16* __restrict__ ol = MlW + (size_t)head * MHEAD16 + SEG16_OFF[s];

    float p[8];
    #pragma unroll
    for (int t = 0; t < 8; ++t) p[t] = (P + t == col_glob) ? 1.0f : 0.0f;

    const int nsub = (ntr > CSROWS) ? 2 : 1;
    #pragma unroll 1
    for (int sub = 0; sub < nsub; ++sub) {
        const int r0 = sub * CSROWS;
        const int nr = (ntr - r0) < CSROWS ? (ntr - r0) : CSROWS;
        const int ne = 8 * nr;

        __syncthreads();                         // csx reuse guard
        float thx[8];
        #pragma unroll
        for (int it = 0; it < 8; ++it) {
            if (it * 64 < ne) {
                int e = lane + it * 64;
                int t = e & 7, jr = r0 + (e >> 3);
                int i = a0 + t;
                thx[it] = th[((i * (255 - i)) >> 1) + jr + 7 - t];
            }
        }
        float thi = 0.0f;
        if (sub == 0 && lane < 28) {
            int t1 = 0, rem = lane;
            while (rem >= 7 - t1) { rem -= 7 - t1; ++t1; }
            int t2 = t1 + 1 + rem;
            int i  = a0 + t1;
            thi = th[((i * (255 - i)) >> 1) + (t2 - t1 - 1)];
        }
        #pragma unroll
        for (int it = 0; it < 8; ++it) {
            if (it * 64 < ne) {
                int e = lane + it * 64;
                float sn, cn; sincos_poly(thx[it], sn, cn);
                csx[56 + 2 * e] = cn; csx[56 + 2 * e + 1] = sn;
            }
        }
        if (sub == 0 && lane < 28) {
            float sn, cn; sincos_poly(thi, sn, cn);
            csx[2 * lane] = cn; csx[2 * lane + 1] = sn;
        }
        __syncthreads();

        if (sub == 0) {                          // intra-group 28 rotations on p
            int idx = 0;
            #pragma unroll
            for (int t1 = 0; t1 < 8; ++t1) {
                #pragma unroll
                for (int t2 = t1 + 1; t2 < 8; ++t2) {
                    float c = csx[2 * idx], sn = csx[2 * idx + 1];
                    float pa = p[t1];
                    p[t1] = fmaf(c, pa,    sn * p[t2]);
                    p[t2] = fmaf(c, p[t2], -(sn * pa));
                    ++idx;
                }
            }
        }

        if (nr > 0) {
            const float* cs = csx + 56;
            const int jv = col_glob - (a0 + 8 + r0);   // local row where v_in = 1
            Row A0, A1, B0, B1;
            ldrow_u(A0, cs); ldrow_u(A1, cs + 16);
            #pragma unroll 1
            for (int r = 0; r < nr; r += 4) {
                ldrow_u(B0, cs + 16 * (r + 2)); ldrow_u(B1, cs + 16 * (r + 3));
                float v0 = rowv(A0, p, (r     == jv) ? 1.0f : 0.0f);
                float v1 = rowv(A1, p, (r + 1 == jv) ? 1.0f : 0.0f);
                store_bf(oh, ol, (8 + r0 + r)     * n + col_local, v0, cact);
                store_bf(oh, ol, (8 + r0 + r + 1) * n + col_local, v1, cact);
                if (r + 4 < nr) { ldrow_u(A0, cs + 16 * (r + 4));
                                  ldrow_u(A1, cs + 16 * (r + 5)); }
                float v2 = rowv(B0, p, (r + 2 == jv) ? 1.0f : 0.0f);
                float v3 = rowv(B1, p, (r + 3 == jv) ? 1.0f : 0.0f);
                store_bf(oh, ol, (8 + r0 + r + 2) * n + col_local, v2, cact);
                store_bf(oh, ol, (8 + r0 + r + 3) * n + col_local, v3, cact);
            }
        }
    }

    #pragma unroll
    for (int t = 0; t < 8; ++t)                  // pivot rows (local rows 0..7)
        store_bf(oh, ol, t * n + col_local, p[t], cact);
}

// ==== Mid/mono-tier chain: R10 Q-path kernel, verbatim ====
__global__ __launch_bounds__(64, 1)
void chain_q(const float* __restrict__ th_all, float* __restrict__ dst_f32,
             u16* __restrict__ MhW, u16* __restrict__ MlW, int mono)
{
    __shared__ float Q[DIM][64];
    __shared__ __align__(16) float csx[56 + CSROWS * 16];

    const int lane = threadIdx.x;
    const int head = blockIdx.x & 63;
    const int unit = blockIdx.x >> 6;

    int s, cb, ng, n;
    if (mono) { s = 0; cb = unit; ng = 16; n = 128; }
    else      { s = U_SEG[unit]; cb = U_CB[unit]; ng = SEG_NG[s]; n = SEG_N[s]; }
    const int P = mono ? 0 : SEG_A[s];
    const int col_local = cb * 64 + lane;
    const int col_glob  = P + col_local;
    const float* __restrict__ th = th_all + head * NROT;

    for (int r = P; r < DIM; ++r)
        QA(r, lane) = (r == col_glob) ? 1.0f : 0.0f;

    #pragma unroll 1
    for (int g = 0; g < ng; ++g) {
        const int a0  = P + 8 * g;
        const int ntr = 120 - a0;
        float p[8];

        const int nsub = (ntr > CSROWS) ? 2 : 1;
        #pragma unroll 1
        for (int sub = 0; sub < nsub; ++sub) {
            const int r0 = sub * CSROWS;
            const int nr = (ntr - r0) < CSROWS ? (ntr - r0) : CSROWS;
            const int ne = 8 * nr;

            __syncthreads();
            float thx[8];
            #pragma unroll
            for (int it = 0; it < 8; ++it) {
                if (it * 64 < ne) {
                    int e = lane + it * 64;
                    int t = e & 7, jr = r0 + (e >> 3);
                    int i = a0 + t;
                    thx[it] = th[((i * (255 - i)) >> 1) + jr + 7 - t];
                }
            }
            float thi = 0.0f;
            if (sub == 0 && lane < 28) {
                int t1 = 0, rem = lane;
                while (rem >= 7 - t1) { rem -= 7 - t1; ++t1; }
                int t2 = t1 + 1 + rem;
                int i  = a0 + t1;
                thi = th[((i * (255 - i)) >> 1) + (t2 - t1 - 1)];
            }
            #pragma unroll
            for (int it = 0; it < 8; ++it) {
                if (it * 64 < ne) {
                    int e = lane + it * 64;
                    float sn, cn; sincos_poly(thx[it], sn, cn);
                    csx[56 + 2 * e] = cn; csx[56 + 2 * e + 1] = sn;
                }
            }
            if (sub == 0 && lane < 28) {
                float sn, cn; sincos_poly(thi, sn, cn);
                csx[2 * lane] = cn; csx[2 * lane + 1] = sn;
            }
            __syncthreads();

            if (sub == 0) {
                #pragma unroll
                for (int t = 0; t < 8; ++t) p[t] = QA(a0 + t, lane);
                int idx = 0;
                #pragma unroll
                for (int t1 = 0; t1 < 8; ++t1) {
                    #pragma unroll
                    for (int t2 = t1 + 1; t2 < 8; ++t2) {
                        float c = csx[2 * idx], sn = csx[2 * idx + 1];
                        float pa = p[t1];
                        p[t1] = fmaf(c, pa,    sn * p[t2]);
                        p[t2] = fmaf(c, p[t2], -(sn * pa));
                        ++idx;
                    }
                }
            }

            if (nr > 0) {
                const float* cs = csx + 56;
                const int base = a0 + 8 + r0;
                Row A0, A1, B0, B1;
                float vA0, vA1, vB0, vB1;
                auto ldpair = [&](Row& R, float& v, int r) {
                    ldrow_u(R, cs + 16 * r);
                    v = QA(base + r, lane);
                };
                ldpair(A0, vA0, 0); ldpair(A1, vA1, 1);
                #pragma unroll 1
                for (int r = 0; r < nr; r += 4) {
                    ldpair(B0, vB0, r + 2); ldpair(B1, vB1, r + 3);
                    rot8(A0, p, vA0); rot8(A1, p, vA1);
                    QA(base + r, lane)     = vA0;
                    QA(base + r + 1, lane) = vA1;
                    if (r + 4 < nr) { ldpair(A0, vA0, r + 4); ldpair(A1, vA1, r + 5); }
                    rot8(B0, p, vB0); rot8(B1, p, vB1);
                    QA(base + r + 2, lane) = vB0;
                    QA(base + r + 3, lane) = vB1;
                }
            }
        }

        #pragma unroll
        for (int t = 0; t < 8; ++t) QA(a0 + t, lane) = p[t];
    }

    __syncthreads();

    if (mono) {
        float* o = dst_f32 + head * (DIM * DIM) + col_glob;
        #pragma unroll 1
        for (int r = 0; r < DIM; ++r) o[r * DIM] = QA(r, lane);
    } else if (col_local < n) {
        u16* oh = MhW + (size_t)head * MHEAD10 + SEG_OFF[s];
        u16* ol = MlW + (size_t)head * MHEAD10 + SEG_OFF[s];
        #pragma unroll 2
        for (int r = 0; r < n; ++r) {
            float v = QA(P + r, lane);
            u16 h = f2bf(v);
            u16 l = f2bf(v - bf2f(h));
            oh[r * n + col_local] = h;
            ol[r * n + col_local] = l;
        }
    }
}

// ==== Compose: MFMA bf16 3-term split; 16-col slices, runtime segment tables ====
__global__ __launch_bounds__(256, 1)
void compose_mfma(const u16* __restrict__ MhA, const u16* __restrict__ MlA,
                  float* __restrict__ out, int cfg, int mhead)
{
    __shared__ u16 AhT[16][KAC];         // 5.25 KB each
    __shared__ u16 AlT[16][KAC];

    const int tid  = threadIdx.x;
    const int lane = tid & 63;
    const int w    = tid >> 6;
    const int head = blockIdx.x & 63;    // all 8 slices of a head -> same XCD
    const int sl   = blockIdx.x >> 6;
    const int c0   = sl * 16;
    const u16* __restrict__ Mh = MhA + (size_t)head * mhead;
    const u16* __restrict__ Ml = MlA + (size_t)head * mhead;

    {   // zero k-pad, then A := M0 slice
        int c = tid & 15, rr = tid >> 4;
        for (int k = DIM + rr; k < KAC; k += 16) { AhT[c][k] = 0; AlT[c][k] = 0; }
        for (int r = rr; r < DIM; r += 16) {
            AhT[c][r] = Mh[r * DIM + c0 + c];
            AlT[c][r] = Ml[r * DIM + c0 + c];
        }
    }
    __syncthreads();

    const int fr  = lane & 15;           // B col / A row within tile / C col
    const int fk  = (lane >> 4) * 8;     // k-slice offset
    const int r4  = (lane >> 4) * 4;     // C row offset
    const int ro0 = 16 * w;
    const int ro1 = 16 * (w + 4);
    const int nseg = CSEG_CNT[cfg];

    #pragma unroll 1
    for (int s = 1; s < nseg; ++s) {
        const int P = CSEG_A[cfg][s], n = CSEG_N[cfg][s], off = CSEG_OFF[cfg][s];
        const int nkt = (n + 31) >> 5;
        const u16* __restrict__ Msh = Mh + off;
        const u16* __restrict__ Msl = Ml + off;
        const bool actA = ro0 < n, actB = ro1 < n;
        const int rA = ro0 + fr, rB = ro1 + fr;

        f4 cA = {0,0,0,0}, cB = {0,0,0,0};
        #pragma unroll 1
        for (int kt = 0; kt < nkt; ++kt) {
            const int kk  = kt * 32 + fk;
            const int kkc = (kk <= n - 8) ? kk : (n - 8);   // clamp global reads
            // shared B-frags (A_old, k-contiguous; rows >= 128 are zero pad)
            bf8 bh = *(const bf8*)&AhT[fr][P + kk];
            bf8 bl = *(const bf8*)&AlT[fr][P + kk];
            if (actA) {
                bf8 ah = *(const bf8*)&Msh[rA * n + kkc];
                bf8 al = *(const bf8*)&Msl[rA * n + kkc];
                cA = __builtin_amdgcn_mfma_f32_16x16x32_bf16(ah, bh, cA, 0, 0, 0);
                cA = __builtin_amdgcn_mfma_f32_16x16x32_bf16(ah, bl, cA, 0, 0, 0);
                cA = __builtin_amdgcn_mfma_f32_16x16x32_bf16(al, bh, cA, 0, 0, 0);
            }
            if (actB) {
                bf8 ah = *(const bf8*)&Msh[rB * n + kkc];
                bf8 al = *(const bf8*)&Msl[rB * n + kkc];
                cB = __builtin_amdgcn_mfma_f32_16x16x32_bf16(ah, bh, cB, 0, 0, 0);
                cB = __builtin_amdgcn_mfma_f32_16x16x32_bf16(ah, bl, cB, 0, 0, 0);
                cB = __builtin_amdgcn_mfma_f32_16x16x32_bf16(al, bh, cB, 0, 0, 0);
            }
        }

        __syncthreads();                 // all reads of old A complete

        auto split_store = [&](const f4& cc, int rg) {
            if (rg < DIM) {              // garbage M rows map to rg >= 128 (P+n==128)
                float v0 = cc[0], v1 = cc[1], v2 = cc[2], v3 = cc[3];
                u16 h0 = f2bf(v0), h1 = f2bf(v1), h2 = f2bf(v2), h3 = f2bf(v3);
                u16 l0 = f2bf(v0 - bf2f(h0)), l1 = f2bf(v1 - bf2f(h1));
                u16 l2 = f2bf(v2 - bf2f(h2)), l3 = f2bf(v3 - bf2f(h3));
                ushort4 hv; hv.x = h0; hv.y = h1; hv.z = h2; hv.w = h3;
                ushort4 lv; lv.x = l0; lv.y = l1; lv.z = l2; lv.w = l3;
                *(ushort4*)&AhT[fr][rg] = hv;
                *(ushort4*)&AlT[fr][rg] = lv;
            }
        };
        split_store(cA, P + ro0 + r4);
        split_store(cB, P + ro1 + r4);
        __syncthreads();                 // new A visible
    }

    {   // output: Q = Ah + Al
        int c = tid & 15, rr = tid >> 4;
        float* o = out + (size_t)head * (DIM * DIM) + c0;
        for (int r = rr; r < DIM; r += 16)
            o[r * DIM + c] = bf2f(AhT[c][r]) + bf2f(AlT[c][r]);
    }
}

extern "C" void kernel_launch(void* const* d_in, const int* in_sizes, int n_in,
                              void* d_out, int out_size, void* d_ws, size_t ws_size,
                              hipStream_t stream) {
    const float* thetas = (const float*)d_in[0];
    float* out = (float*)d_out;
    const size_t need16 = (size_t)NHEAD * MHEAD16 * 2 * sizeof(u16);  // 24.5 MB
    const size_t need10 = (size_t)NHEAD * MHEAD10 * 2 * sizeof(u16);  // 22.8 MB

    if (ws_size >= need16) {
        u16* MhW = (u16*)d_ws;
        u16* MlW = MhW + (size_t)NHEAD * MHEAD16;
        chain16<<<dim3(NUNIT16 * NHEAD), dim3(64), 0, stream>>>(thetas, MhW, MlW);
        compose_mfma<<<dim3(8 * NHEAD), dim3(256), 0, stream>>>(MhW, MlW, out, 0, MHEAD16);
    } else if (ws_size >= need10) {
        u16* MhW = (u16*)d_ws;
        u16* MlW = MhW + (size_t)NHEAD * MHEAD10;
        chain_q<<<dim3(NUNIT10 * NHEAD), dim3(64), 0, stream>>>(thetas, nullptr, MhW, MlW, 0);
        compose_mfma<<<dim3(8 * NHEAD), dim3(256), 0, stream>>>(MhW, MlW, out, 1, MHEAD10);
    } else {
        chain_q<<<dim3(2 * NHEAD), dim3(64), 0, stream>>>(thetas, out, nullptr, nullptr, 1);
    }
}

// Round 12
// 41.631 us; speedup vs baseline: 3.0617x; 1.2528x over previous
//
#include <hip/hip_runtime.h>

#define DIM 128
#define NHEAD 64
#define NROT 8128
#define NSEG28 28
#define MHEAD28 57344          // sum n_s^2, 28 sub-chunks
#define KAC 168                // compose LDS k-dim (128 data + zero pad)
#define CSROWS 64              // mono fallback staging

typedef float f4 __attribute__((ext_vector_type(4)));
typedef short bf8 __attribute__((ext_vector_type(8)));
typedef unsigned short u16;

// 28 sub-chunk segments: rotations {(a0+t, j): j in [j0, j0+nj)}, support
// {a0..a0+7} u [j0, j0+nj). Chunk0 of each group also carries the 28 intra rots.
__device__ const int S_A0[NSEG28] = {0,0,0,8,8,8,16,16,16,24,24,32,32,40,40,
                                     48,48,56,56,64,64,72,80,88,96,104,112,120};
__device__ const int S_J0[NSEG28] = {8,56,104,16,64,112,24,72,120,32,80,40,88,48,96,
                                     56,104,64,112,72,120,80,88,96,104,112,120,128};
__device__ const int S_NJ[NSEG28] = {48,48,24,48,48,16,48,48,8,48,48,48,40,48,32,
                                     48,24,48,16,48,8,48,40,32,24,16,8,0};
__device__ const int S_OFF[NSEG28] = {0,3136,6272,7296,10432,13568,14144,17280,20416,
                                      20672,23808,26944,30080,32384,35520,37120,40256,
                                      41280,44416,44992,48128,48384,51520,53824,55424,
                                      56448,57024,57280};
__device__ const int S_INTRA[NSEG28] = {1,0,0,1,0,0,1,0,0,1,0,1,0,1,0,
                                        1,0,1,0,1,0,1,1,1,1,1,1,1};

// |theta| <= ~0.06: degree-5/4 Taylor, error ~1e-11
__device__ __forceinline__ void sincos_poly(float x, float& sn, float& cn) {
    float x2 = x * x;
    sn = x * fmaf(x2, fmaf(x2, 8.33333333e-3f, -1.66666667e-1f), 1.0f);
    cn = fmaf(x2, fmaf(x2, 4.16666667e-2f, -0.5f), 1.0f);
}

__device__ __forceinline__ u16 f2bf(float v) {          // RNE f32 -> bf16 bits
    unsigned b = __float_as_uint(v);
    b += 0x7FFF + ((b >> 16) & 1);
    return (u16)(b >> 16);
}
__device__ __forceinline__ float bf2f(u16 h) {
    return __uint_as_float(((unsigned)h) << 16);
}

struct Row { f4 q0, q1, q2, q3; };   // 8 (c,s) pairs for one trailing row

__device__ __forceinline__ void ldrow_u(Row& R, const float* p) {
    const f4* c4 = (const f4*)p;
    R.q0 = c4[0]; R.q1 = c4[1]; R.q2 = c4[2]; R.q3 = c4[3];
}

// v-chain for one trailing row: v_in known constant, p in registers.
__device__ __forceinline__ float rowv(const Row& R, float p[8], float v) {
#define ROT2(c, s, T) { float pv = p[T]; float nv = fmaf((c), v, -((s) * pv)); \
                        p[T] = fmaf((s), v, (c) * pv); v = nv; }
    ROT2(R.q0.x, R.q0.y, 0) ROT2(R.q0.z, R.q0.w, 1)
    ROT2(R.q1.x, R.q1.y, 2) ROT2(R.q1.z, R.q1.w, 3)
    ROT2(R.q2.x, R.q2.y, 4) ROT2(R.q2.z, R.q2.w, 5)
    ROT2(R.q3.x, R.q3.y, 6) ROT2(R.q3.z, R.q3.w, 7)
#undef ROT2
    return v;
}

__device__ __forceinline__ void store_bf(u16* oh, u16* ol, int idx, float v, bool act) {
    u16 h = f2bf(v);
    u16 l = f2bf(v - bf2f(h));
    if (act) { oh[idx] = h; ol[idx] = l; }
}

// ==== Phase 1: Q-less sub-chunk chain (28 units/head, max 48 serial rows) ====
__global__ __launch_bounds__(64, 1)
void chain28(const float* __restrict__ th_all,
             u16* __restrict__ MhW, u16* __restrict__ MlW)
{
    __shared__ __align__(16) float csx[56 + 48 * 16];   // 3.3 KB

    const int lane = threadIdx.x;
    const int head = blockIdx.x & 63;        // XCD = head%8 for producer+consumer
    const int s    = blockIdx.x >> 6;
    const int a0 = S_A0[s], j0 = S_J0[s], nj = S_NJ[s], n = 8 + nj;
    const bool intra = S_INTRA[s] != 0;
    const float* __restrict__ th = th_all + head * NROT;
    u16* __restrict__ oh = MhW + (size_t)head * MHEAD28 + S_OFF[s];
    u16* __restrict__ ol = MlW + (size_t)head * MHEAD28 + S_OFF[s];
    const bool cact = lane < n;
    const int ne = 8 * nj;
    const int d1 = j0 - a0 - 1;              // theta: idx = base_i + d1 - t + jr

    // batched theta loads (independent -> one latency exposure)
    float thx[6];
    #pragma unroll
    for (int it = 0; it < 6; ++it) {
        if (it * 64 < ne) {
            int e = lane + it * 64;
            int t = e & 7, jr = e >> 3;
            int i = a0 + t;
            thx[it] = th[((i * (255 - i)) >> 1) + d1 - t + jr];
        }
    }
    float thi = 0.0f;
    if (intra && lane < 28) {
        int t1 = 0, rem = lane;
        while (rem >= 7 - t1) { rem -= 7 - t1; ++t1; }
        int t2 = t1 + 1 + rem;
        int i  = a0 + t1;
        thi = th[((i * (255 - i)) >> 1) + (t2 - t1 - 1)];
    }
    #pragma unroll
    for (int it = 0; it < 6; ++it) {
        if (it * 64 < ne) {
            int e = lane + it * 64;
            float sn, cn; sincos_poly(thx[it], sn, cn);
            csx[56 + 2 * e] = cn; csx[56 + 2 * e + 1] = sn;
        }
    }
    if (intra && lane < 28) {
        float sn, cn; sincos_poly(thi, sn, cn);
        csx[2 * lane] = cn; csx[2 * lane + 1] = sn;
    }
    __syncthreads();

    float p[8];
    #pragma unroll
    for (int t = 0; t < 8; ++t) p[t] = (lane == t) ? 1.0f : 0.0f;

    if (intra) {                             // 28 pivot-pivot rotations
        int idx = 0;
        #pragma unroll
        for (int t1 = 0; t1 < 8; ++t1) {
            #pragma unroll
            for (int t2 = t1 + 1; t2 < 8; ++t2) {
                float c = csx[2 * idx], sn = csx[2 * idx + 1];
                float pa = p[t1];
                p[t1] = fmaf(c, pa,    sn * p[t2]);
                p[t2] = fmaf(c, p[t2], -(sn * pa));
                ++idx;
            }
        }
    }

    if (nj > 0) {
        const float* cs = csx + 56;
        const int jv = lane - 8;             // local trailing row where v_in = 1
        Row A0, A1, B0, B1;
        ldrow_u(A0, cs); ldrow_u(A1, cs + 16);
        #pragma unroll 1
        for (int r = 0; r < nj; r += 4) {
            ldrow_u(B0, cs + 16 * (r + 2)); ldrow_u(B1, cs + 16 * (r + 3));
            float v0 = rowv(A0, p, (r     == jv) ? 1.0f : 0.0f);
            float v1 = rowv(A1, p, (r + 1 == jv) ? 1.0f : 0.0f);
            store_bf(oh, ol, (8 + r)     * n + lane, v0, cact);
            store_bf(oh, ol, (8 + r + 1) * n + lane, v1, cact);
            if (r + 4 < nj) { ldrow_u(A0, cs + 16 * (r + 4));
                              ldrow_u(A1, cs + 16 * (r + 5)); }
            float v2 = rowv(B0, p, (r + 2 == jv) ? 1.0f : 0.0f);
            float v3 = rowv(B1, p, (r + 3 == jv) ? 1.0f : 0.0f);
            store_bf(oh, ol, (8 + r + 2) * n + lane, v2, cact);
            store_bf(oh, ol, (8 + r + 3) * n + lane, v3, cact);
        }
    }

    #pragma unroll
    for (int t = 0; t < 8; ++t)
        store_bf(oh, ol, t * n + lane, p[t], cact);
}

// ==== Phase 2: MFMA compose, 2-range row mapping, 4-term bf16 split ====
__global__ __launch_bounds__(256, 1)
void compose28(const u16* __restrict__ MhA, const u16* __restrict__ MlA,
               float* __restrict__ out)
{
    __shared__ u16 AhT[16][KAC];             // 5.25 KB each; rows >=128 = zero pad
    __shared__ u16 AlT[16][KAC];

    const int tid  = threadIdx.x;
    const int lane = tid & 63;
    const int w    = tid >> 6;
    const int head = blockIdx.x & 63;        // all 8 slices -> same XCD as producer
    const int sl   = blockIdx.x >> 6;
    const int c0   = sl * 16;
    const u16* __restrict__ Mh = MhA + (size_t)head * MHEAD28;
    const u16* __restrict__ Ml = MlA + (size_t)head * MHEAD28;

    {   // zero k-pad, then A := embedded M_0 (support rows/cols [0,56))
        int c = tid & 15, rr = tid >> 4, cg = c0 + c;
        for (int k = DIM + rr; k < KAC; k += 16) { AhT[c][k] = 0; AlT[c][k] = 0; }
        for (int r = rr; r < DIM; r += 16) {
            u16 h, l;
            if (r < 56 && cg < 56) { h = Mh[r * 56 + cg]; l = Ml[r * 56 + cg]; }
            else                   { h = (r == cg) ? (u16)0x3F80 : (u16)0; l = 0; }
            AhT[c][r] = h; AlT[c][r] = l;
        }
    }
    __syncthreads();

    const int fr = lane & 15;                // M row in tile / C col
    const int fk = (lane >> 4) * 8;          // k-slice offset
    const int r4 = (lane >> 4) * 4;          // C row quad offset
    const int ro = 16 * w;                   // wave's tile row base

    #pragma unroll 1
    for (int s = 1; s < NSEG28; ++s) {
        const int a0 = S_A0[s], j0 = S_J0[s], n = 8 + S_NJ[s];
        const int nkt = (n + 31) >> 5;
        const u16* __restrict__ Msh = Mh + S_OFF[s];
        const u16* __restrict__ Msl = Ml + S_OFF[s];
        const bool act = ro < n;             // wave-uniform
        const int rA  = ro + fr;
        const int rAc = (rA < n) ? rA : (n - 1);   // clamp (garbage rows unguarded by store)

        f4 cA = {0, 0, 0, 0};
        #pragma unroll 1
        for (int kt = 0; kt < nkt; ++kt) {
            const int kk  = kt * 32 + fk;
            const int kkc = (kk <= n - 8) ? kk : (n - 8);
            // 2-range k -> A-row map; k >= n hits the zero pad (row 128)
            const int brow = (kk < 8) ? (a0 + kk) : ((kk < n) ? (j0 + kk - 8) : 128);
            bf8 bh = *(const bf8*)&AhT[fr][brow];
            bf8 bl = *(const bf8*)&AlT[fr][brow];
            if (act) {
                bf8 ah = *(const bf8*)&Msh[rAc * n + kkc];
                bf8 al = *(const bf8*)&Msl[rAc * n + kkc];
                cA = __builtin_amdgcn_mfma_f32_16x16x32_bf16(ah, bh, cA, 0, 0, 0);
                cA = __builtin_amdgcn_mfma_f32_16x16x32_bf16(ah, bl, cA, 0, 0, 0);
                cA = __builtin_amdgcn_mfma_f32_16x16x32_bf16(al, bh, cA, 0, 0, 0);
                cA = __builtin_amdgcn_mfma_f32_16x16x32_bf16(al, bl, cA, 0, 0, 0);
            }
        }

        __syncthreads();                     // all reads of old A complete

        const int rowq = ro + r4;            // quad never straddles 8 or n (both mult 4/8)
        if (act && rowq < n) {
            const int rg = (rowq < 8) ? (a0 + rowq) : (j0 + rowq - 8);
            float v0 = cA[0], v1 = cA[1], v2 = cA[2], v3 = cA[3];
            u16 h0 = f2bf(v0), h1 = f2bf(v1), h2 = f2bf(v2), h3 = f2bf(v3);
            u16 l0 = f2bf(v0 - bf2f(h0)), l1 = f2bf(v1 - bf2f(h1));
            u16 l2 = f2bf(v2 - bf2f(h2)), l3 = f2bf(v3 - bf2f(h3));
            ushort4 hv; hv.x = h0; hv.y = h1; hv.z = h2; hv.w = h3;
            ushort4 lv; lv.x = l0; lv.y = l1; lv.z = l2; lv.w = l3;
            *(ushort4*)&AhT[fr][rg] = hv;
            *(ushort4*)&AlT[fr][rg] = lv;
        }
        __syncthreads();                     // new A visible
    }

    {   // output: Q = Ah + Al
        int c = tid & 15, rr = tid >> 4;
        float* o = out + (size_t)head * (DIM * DIM) + c0;
        for (int r = rr; r < DIM; r += 16)
            o[r * DIM + c] = bf2f(AhT[c][r]) + bf2f(AlT[c][r]);
    }
}

// ==== Fallback: monolithic Q-in-LDS chain (proven R7 structure), tiny-ws only ====
#define QA(r, c) Q[(r)][ (c) ^ ((r) & 31) ]
#define ROTP(c, s, T, v) { float pt = p[T]; p[T] = fmaf((c), pt, (s) * (v)); \
                           (v) = fmaf((c), (v), -((s) * pt)); }
__device__ __forceinline__ void rot8q(const Row& r, float p[8], float& v) {
    ROTP(r.q0.x, r.q0.y, 0, v) ROTP(r.q0.z, r.q0.w, 1, v)
    ROTP(r.q1.x, r.q1.y, 2, v) ROTP(r.q1.z, r.q1.w, 3, v)
    ROTP(r.q2.x, r.q2.y, 4, v) ROTP(r.q2.z, r.q2.w, 5, v)
    ROTP(r.q3.x, r.q3.y, 6, v) ROTP(r.q3.z, r.q3.w, 7, v)
}

__global__ __launch_bounds__(64, 1)
void chain_mono(const float* __restrict__ th_all, float* __restrict__ outp)
{
    __shared__ float Q[DIM][64];
    __shared__ __align__(16) float csx[56 + CSROWS * 16];

    const int lane = threadIdx.x;
    const int head = blockIdx.x & 63;
    const int cb   = blockIdx.x >> 6;
    const int col_glob = cb * 64 + lane;
    const float* __restrict__ th = th_all + head * NROT;

    for (int r = 0; r < DIM; ++r)
        QA(r, lane) = (r == col_glob) ? 1.0f : 0.0f;

    #pragma unroll 1
    for (int g = 0; g < 16; ++g) {
        const int a0  = 8 * g;
        const int ntr = 120 - a0;
        float p[8];
        const int nsub = (ntr > CSROWS) ? 2 : 1;
        #pragma unroll 1
        for (int sub = 0; sub < nsub; ++sub) {
            const int r0 = sub * CSROWS;
            const int nr = (ntr - r0) < CSROWS ? (ntr - r0) : CSROWS;
            const int ne = 8 * nr;
            __syncthreads();
            float thx[8];
            #pragma unroll
            for (int it = 0; it < 8; ++it) {
                if (it * 64 < ne) {
                    int e = lane + it * 64;
                    int t = e & 7, jr = r0 + (e >> 3);
                    int i = a0 + t;
                    thx[it] = th[((i * (255 - i)) >> 1) + jr + 7 - t];
                }
            }
            float thi = 0.0f;
            if (sub == 0 && lane < 28) {
                int t1 = 0, rem = lane;
                while (rem >= 7 - t1) { rem -= 7 - t1; ++t1; }
                int t2 = t1 + 1 + rem;
                int i  = a0 + t1;
                thi = th[((i * (255 - i)) >> 1) + (t2 - t1 - 1)];
            }
            #pragma unroll
            for (int it = 0; it < 8; ++it) {
                if (it * 64 < ne) {
                    int e = lane + it * 64;
                    float sn, cn; sincos_poly(thx[it], sn, cn);
                    csx[56 + 2 * e] = cn; csx[56 + 2 * e + 1] = sn;
                }
            }
            if (sub == 0 && lane < 28) {
                float sn, cn; sincos_poly(thi, sn, cn);
                csx[2 * lane] = cn; csx[2 * lane + 1] = sn;
            }
            __syncthreads();

            if (sub == 0) {
                #pragma unroll
                for (int t = 0; t < 8; ++t) p[t] = QA(a0 + t, lane);
                int idx = 0;
                #pragma unroll
                for (int t1 = 0; t1 < 8; ++t1) {
                    #pragma unroll
                    for (int t2 = t1 + 1; t2 < 8; ++t2) {
                        float c = csx[2 * idx], sn = csx[2 * idx + 1];
                        float pa = p[t1];
                        p[t1] = fmaf(c, pa,    sn * p[t2]);
                        p[t2] = fmaf(c, p[t2], -(sn * pa));
                        ++idx;
                    }
                }
            }
            if (nr > 0) {
                const float* cs = csx + 56;
                const int base = a0 + 8 + r0;
                Row A0, A1, B0, B1;
                float vA0, vA1, vB0, vB1;
                auto ldpair = [&](Row& R, float& v, int r) {
                    ldrow_u(R, cs + 16 * r);
                    v = QA(base + r, lane);
                };
                ldpair(A0, vA0, 0); ldpair(A1, vA1, 1);
                #pragma unroll 1
                for (int r = 0; r < nr; r += 4) {
                    ldpair(B0, vB0, r + 2); ldpair(B1, vB1, r + 3);
                    rot8q(A0, p, vA0); rot8q(A1, p, vA1);
                    QA(base + r, lane)     = vA0;
                    QA(base + r + 1, lane) = vA1;
                    if (r + 4 < nr) { ldpair(A0, vA0, r + 4); ldpair(A1, vA1, r + 5); }
                    rot8q(B0, p, vB0); rot8q(B1, p, vB1);
                    QA(base + r + 2, lane) = vB0;
                    QA(base + r + 3, lane) = vB1;
                }
            }
        }
        #pragma unroll
        for (int t = 0; t < 8; ++t) QA(a0 + t, lane) = p[t];
    }

    __syncthreads();
    float* o = outp + head * (DIM * DIM) + col_glob;
    #pragma unroll 1
    for (int r = 0; r < DIM; ++r) o[r * DIM] = QA(r, lane);
}

extern "C" void kernel_launch(void* const* d_in, const int* in_sizes, int n_in,
                              void* d_out, int out_size, void* d_ws, size_t ws_size,
                              hipStream_t stream) {
    const float* thetas = (const float*)d_in[0];
    float* out = (float*)d_out;
    const size_t need = (size_t)NHEAD * MHEAD28 * 2 * sizeof(u16);  // 14.7 MB

    if (ws_size >= need) {
        u16* MhW = (u16*)d_ws;
        u16* MlW = MhW + (size_t)NHEAD * MHEAD28;
        chain28<<<dim3(NSEG28 * NHEAD), dim3(64), 0, stream>>>(thetas, MhW, MlW);
        compose28<<<dim3(8 * NHEAD), dim3(256), 0, stream>>>(MhW, MlW, out);
    } else {
        chain_mono<<<dim3(2 * NHEAD), dim3(64), 0, stream>>>(thetas, out);
    }
}